// Round 8
// baseline (245.421 us; speedup 1.0000x reference)
//
#include <hip/hip_runtime.h>

#define B_ 1024
#define D_ 512
#define T_ 36
#define NT_ 64
#define DS_ 32
#define EPS_ 1e-5f

typedef float f32x4 __attribute__((ext_vector_type(4)));
typedef __bf16 bf16x8 __attribute__((ext_vector_type(8)));
typedef unsigned short u16x8 __attribute__((ext_vector_type(8)));
typedef unsigned short u16x4 __attribute__((ext_vector_type(4)));

#define DEVI static __device__ __forceinline__
#define MFMA16 __builtin_amdgcn_mfma_f32_16x16x32_bf16

DEVI unsigned short f2bf(float f) { return __builtin_bit_cast(unsigned short, (__bf16)f); }
DEVI float bf2f(unsigned short h) { return (float)__builtin_bit_cast(__bf16, h); }

// XOR-swizzled byte offset inside a [48 rows][1024B] transposed image (T2)
DEVI unsigned swz(int row, int col) {   // col in ushort elements (0..511)
    return (unsigned)(row * 1024 + ((2 * col) ^ ((row & 7) << 4)));
}

// ---- K1 LDS layout (total 81,664 B -> 2 blocks/CU) ----
// R0 @0 [49,152]: ysT image (P0-P1) -> ynat [512][80B] @0 + a2 [48][72]u16 @40,960 -> h image (P6-P7)
// SC @49,152 [9,472]: sc f32 [64][37] ; red overlay in P6
// A1 @58,624 [9,216]: a1 u16 [64][72]
// A1T @67,840 [6,912]: a1t u16 [48][72]
// GT @74,752 [6,912]: gt u16 [48][72] -> W overlay after P3
#define LDS_A2  40960
#define LDS_SC  49152
#define LDS_A1  58624
#define LDS_A1T 67840
#define LDS_GT  74752
#define K1_LDS  81664

// ---- K0: prepack tok bf16 [64][512], tokT bf16 [512][64], block-diag wd bf16 [32][512] ----
__global__ __launch_bounds__(512)
void k0_prepack(const float* __restrict__ tok, const float* __restrict__ wd,
                unsigned short* __restrict__ tokbf, unsigned short* __restrict__ tokT,
                unsigned short* __restrict__ wdd)
{
    int i = blockIdx.x * 512 + threadIdx.x;
    if (i < 32768) {
        tokbf[i] = f2bf(tok[i]);
    } else if (i < 65536) {
        int j = i - 32768; int d = j >> 6, t = j & 63;
        tokT[j] = f2bf(tok[t * 512 + d]);
    } else if (i < 81920) {
        int j = i - 65536; int o = j >> 9, dd = j & 511;
        wdd[j] = ((dd >> 7) == (o >> 3)) ? f2bf(wd[o * 128 + (dd & 127)]) : (unsigned short)0;
    }
}

// ---- KA: per-batch transpose x -> xT bf16 [48][512] (rows 36..47 zero) ----
__global__ __launch_bounds__(512)
void kA_xpose(const float* __restrict__ x, unsigned short* __restrict__ xT, int b0)
{
    __shared__ char sl[49152];
    const int b = b0 + blockIdx.x;
    const int tid = threadIdx.x;
    const float* xb = x + b * (D_ * T_);
    unsigned short* xTb = xT + (size_t)blockIdx.x * 24576;

    for (int u = tid; u < 576; u += 512) {
        int dblk = u / 9, s4 = u - dblk * 9;
        int s0 = s4 * 4;
        const float* bp = xb + dblk * 8 * T_ + s0;
        u16x8 u0, u1, u2, u3;
        #pragma unroll
        for (int r = 0; r < 8; ++r) {
            f32x4 v = *(const f32x4*)(bp + r * T_);
            u0[r] = f2bf(v[0]); u1[r] = f2bf(v[1]);
            u2[r] = f2bf(v[2]); u3[r] = f2bf(v[3]);
        }
        *(u16x8*)(sl + swz(s0 + 0, dblk * 8)) = u0;
        *(u16x8*)(sl + swz(s0 + 1, dblk * 8)) = u1;
        *(u16x8*)(sl + swz(s0 + 2, dblk * 8)) = u2;
        *(u16x8*)(sl + swz(s0 + 3, dblk * 8)) = u3;
    }
    __syncthreads();
    for (int i = tid; i < 2304; i += 512) {
        int row = i >> 6, l = i & 63;
        *(u16x8*)(xTb + row * 512 + l * 8) = *(const u16x8*)(sl + swz(row, l * 8));
    }
    for (int i = tid; i < 3072; i += 512)
        ((unsigned*)(xTb + 36 * 512))[i] = 0u;
}

// =================== K1: fused attention + LN + downconv (512 thr, 2 blocks/CU) ===================
__global__ __launch_bounds__(512, 4)
void k1_fused(const unsigned short* __restrict__ xT, const float* __restrict__ y,
              const unsigned short* __restrict__ tokbf, const unsigned short* __restrict__ tokT,
              const float* __restrict__ gav_p, const unsigned short* __restrict__ wdd,
              const float* __restrict__ lnbg, const float* __restrict__ lnbb,
              float* __restrict__ z_pre, int b0)
{
    extern __shared__ char lds[];
    float* sc = (float*)(lds + LDS_SC);
    unsigned short* a1  = (unsigned short*)(lds + LDS_A1);
    unsigned short* a1t = (unsigned short*)(lds + LDS_A1T);
    unsigned short* gt  = (unsigned short*)(lds + LDS_GT);
    unsigned short* wb  = gt;                              // W overlays gt after P3
    unsigned short* a2  = (unsigned short*)(lds + LDS_A2); // inside R0 tail

    const int b    = b0 + blockIdx.x;
    const int tid  = threadIdx.x;
    const int lane = tid & 63;
    const int w    = tid >> 6;   // 0..7
    const int l15  = lane & 15;
    const int l4   = lane >> 4;  // 0..3

    const float* yb = y + b * (D_ * T_);
    const unsigned short* xTb = xT + (size_t)blockIdx.x * 24576;

    // ---- P0: zero pads (ysT rows 36..47; a1/a1t/gt contiguous) + stage ysT image ----
    {
        unsigned* z1 = (unsigned*)(lds + 36 * 1024);
        for (int i = tid; i < 3072; i += 512) z1[i] = 0u;
        unsigned* z3 = (unsigned*)(lds + LDS_A1);   // 23,040 B contiguous
        for (int i = tid; i < 5760; i += 512) z3[i] = 0u;
    }
    for (int u = tid; u < 576; u += 512) {
        int dblk = u / 9, s4 = u - dblk * 9;
        int s0 = s4 * 4;
        const float* bp = yb + dblk * 8 * T_ + s0;
        u16x8 u0, u1, u2, u3;
        #pragma unroll
        for (int r = 0; r < 8; ++r) {
            f32x4 v = *(const f32x4*)(bp + r * T_);
            u0[r] = f2bf(v[0]); u1[r] = f2bf(v[1]);
            u2[r] = f2bf(v[2]); u3[r] = f2bf(v[3]);
        }
        *(u16x8*)(lds + swz(s0 + 0, dblk * 8)) = u0;
        *(u16x8*)(lds + swz(s0 + 1, dblk * 8)) = u1;
        *(u16x8*)(lds + swz(s0 + 2, dblk * 8)) = u2;
        *(u16x8*)(lds + swz(s0 + 3, dblk * 8)) = u3;
    }
    __syncthreads();

    // ---- P1: G1 (S1 = tok@y, 12 tiles) + Gram (gt[sx][sy] = x^T y, 9 tiles; A from global xT) ----
    for (int tl = w; tl < 21; tl += 8) {
        f32x4 acc0 = {0.f,0.f,0.f,0.f}, acc1 = {0.f,0.f,0.f,0.f};
        if (tl < 12) {
            int mt = tl / 3, nt = tl % 3;
            int trow = mt * 16 + l15, srow = nt * 16 + l15;
            #pragma unroll
            for (int ks = 0; ks < 16; ks += 2) {
                int ka = ks * 32 + l4 * 8, kb = ka + 32;
                acc0 = MFMA16(*(const bf16x8*)(tokbf + trow * 512 + ka),
                              *(const bf16x8*)(lds + swz(srow, ka)), acc0, 0, 0, 0);
                acc1 = MFMA16(*(const bf16x8*)(tokbf + trow * 512 + kb),
                              *(const bf16x8*)(lds + swz(srow, kb)), acc1, 0, 0, 0);
            }
            f32x4 acc = acc0 + acc1;
            if (srow < T_) {
                #pragma unroll
                for (int j = 0; j < 4; ++j)
                    sc[(mt * 16 + l4 * 4 + j) * 37 + srow] = acc[j];
            }
        } else {
            int g2 = tl - 12;
            int mt = g2 / 3, nt = g2 % 3;
            int arow = mt * 16 + l15, brow = nt * 16 + l15;
            #pragma unroll
            for (int ks = 0; ks < 16; ks += 2) {
                int ka = ks * 32 + l4 * 8, kb = ka + 32;
                acc0 = MFMA16(*(const bf16x8*)(xTb + arow * 512 + ka),
                              *(const bf16x8*)(lds + swz(brow, ka)), acc0, 0, 0, 0);
                acc1 = MFMA16(*(const bf16x8*)(xTb + arow * 512 + kb),
                              *(const bf16x8*)(lds + swz(brow, kb)), acc1, 0, 0, 0);
            }
            f32x4 acc = acc0 + acc1;
            #pragma unroll
            for (int j = 0; j < 4; ++j)
                gt[(mt * 16 + l4 * 4 + j) * 72 + brow] = f2bf(acc[j]);
        }
    }
    __syncthreads();

    // ---- sm1 (softmax over s per t -> a1 and a1t) || ynat restage over dead ysT ----
    {
        int t = tid >> 3, l8 = tid & 7;
        const float* scp = sc + t * 37;
        float v0 = scp[l8], v1 = scp[l8 + 8], v2 = scp[l8 + 16], v3 = scp[l8 + 24];
        float v4 = (l8 < 4) ? scp[l8 + 32] : -1e30f;
        float m = fmaxf(fmaxf(fmaxf(v0, v1), fmaxf(v2, v3)), v4);
        #pragma unroll
        for (int off = 1; off < 8; off <<= 1) m = fmaxf(m, __shfl_xor(m, off));
        float e0 = __expf(v0 - m), e1 = __expf(v1 - m), e2 = __expf(v2 - m), e3 = __expf(v3 - m);
        float e4 = (l8 < 4) ? __expf(v4 - m) : 0.f;
        float ssum = e0 + e1 + e2 + e3 + e4;
        #pragma unroll
        for (int off = 1; off < 8; off <<= 1) ssum += __shfl_xor(ssum, off);
        float inv = 1.f / ssum;
        unsigned short h0 = f2bf(e0 * inv), h1 = f2bf(e1 * inv);
        unsigned short h2 = f2bf(e2 * inv), h3 = f2bf(e3 * inv);
        a1[t * 72 + l8]      = h0;  a1t[l8 * 72 + t]        = h0;
        a1[t * 72 + l8 + 8]  = h1;  a1t[(l8 + 8) * 72 + t]  = h1;
        a1[t * 72 + l8 + 16] = h2;  a1t[(l8 + 16) * 72 + t] = h2;
        a1[t * 72 + l8 + 24] = h3;  a1t[(l8 + 24) * 72 + t] = h3;
        if (l8 < 4) {
            unsigned short h4 = f2bf(e4 * inv);
            a1[t * 72 + l8 + 32] = h4;
            a1t[(l8 + 32) * 72 + t] = h4;
        }
    }
    // ynat[d][s] bf16 pitch 80B over R0 (rows 0..511); cols 36..39 zeroed
    for (int j = tid; j < 4608; j += 512) {
        int row = j / 9, q = j - row * 9;
        f32x4 v = *(const f32x4*)(yb + row * T_ + q * 4);
        u16x4 hh;
        #pragma unroll
        for (int jj = 0; jj < 4; ++jj) hh[jj] = f2bf(v[jj]);
        *(u16x4*)(lds + row * 80 + q * 8) = hh;
    }
    {
        u16x4 z4 = {0, 0, 0, 0};
        *(u16x4*)(lds + tid * 80 + 72) = z4;
    }
    __syncthreads();

    // ---- P3: S2[t][s] = tok@x (B from global xT) + a1@gt^T ----
    for (int tl = w; tl < 12; tl += 8) {
        int mt = tl / 3, nt = tl % 3;
        int trow = mt * 16 + l15, srow = nt * 16 + l15;
        f32x4 acc0 = {0.f,0.f,0.f,0.f}, acc1 = {0.f,0.f,0.f,0.f};
        #pragma unroll
        for (int ks = 0; ks < 16; ks += 2) {
            int ka = ks * 32 + l4 * 8, kb = ka + 32;
            acc0 = MFMA16(*(const bf16x8*)(tokbf + trow * 512 + ka),
                          *(const bf16x8*)(xTb + srow * 512 + ka), acc0, 0, 0, 0);
            acc1 = MFMA16(*(const bf16x8*)(tokbf + trow * 512 + kb),
                          *(const bf16x8*)(xTb + srow * 512 + kb), acc1, 0, 0, 0);
        }
        acc0 = MFMA16(*(const bf16x8*)(a1 + trow * 72 + l4 * 8),
                      *(const bf16x8*)(gt + srow * 72 + l4 * 8), acc0, 0, 0, 0);
        acc1 = MFMA16(*(const bf16x8*)(a1 + trow * 72 + 32 + l4 * 8),
                      *(const bf16x8*)(gt + srow * 72 + 32 + l4 * 8), acc1, 0, 0, 0);
        f32x4 acc = acc0 + acc1;
        if (srow < T_) {
            #pragma unroll
            for (int j = 0; j < 4; ++j)
                sc[(mt * 16 + l4 * 4 + j) * 37 + srow] = acc[j];
        }
    }
    __syncthreads();

    // ---- sm2: softmax over t per s -> a2 [s][t] (in R0 tail) ----
    if ((tid >> 3) < T_) {
        int s = tid >> 3, l8 = tid & 7;
        float v[8];
        #pragma unroll
        for (int k = 0; k < 8; ++k) v[k] = sc[(l8 + 8 * k) * 37 + s];
        float m = v[0];
        #pragma unroll
        for (int k = 1; k < 8; ++k) m = fmaxf(m, v[k]);
        #pragma unroll
        for (int off = 1; off < 8; off <<= 1) m = fmaxf(m, __shfl_xor(m, off));
        float e[8], ssum = 0.f;
        #pragma unroll
        for (int k = 0; k < 8; ++k) { e[k] = __expf(v[k] - m); ssum += e[k]; }
        #pragma unroll
        for (int off = 1; off < 8; off <<= 1) ssum += __shfl_xor(ssum, off);
        float inv = 1.f / ssum;
        #pragma unroll
        for (int k = 0; k < 8; ++k) a2[s * 72 + l8 + 8 * k] = f2bf(e[k] * inv);
    }
    __syncthreads();

    // ---- P5: W[s2][s1] = a2 @ a1t^T (9 tiles; overlays gt) ----
    for (int tl = w; tl < 9; tl += 8) {
        int mt = tl / 3, nt = tl % 3;
        f32x4 acc = {0.f,0.f,0.f,0.f};
        #pragma unroll
        for (int ks = 0; ks < 2; ++ks) {
            int k0 = ks * 32 + l4 * 8;
            acc = MFMA16(*(const bf16x8*)(a2 + (mt * 16 + l15) * 72 + k0),
                         *(const bf16x8*)(a1t + (nt * 16 + l15) * 72 + k0), acc, 0, 0, 0);
        }
        #pragma unroll
        for (int j = 0; j < 4; ++j)
            wb[(mt * 16 + l4 * 4 + j) * 72 + nt * 16 + l15] = f2bf(acc[j]);
    }
    __syncthreads();

    // ---- P6: xresT[d][s] = tokT@a2^T + ynat@W^T ; xc ; LN -> h image (R0 overlay) ----
    {
        const float gav = gav_p[0];
        float* red = sc;   // dead sc overlay: [8][40]x2 + mu/rsig
        f32x4 acc[3][4];
        #pragma unroll
        for (int st = 0; st < 3; ++st) {
            int sbase = st * 16;
            bf16x8 b10 = *(const bf16x8*)(a2 + (sbase + l15) * 72 + l4 * 8);
            bf16x8 b11 = *(const bf16x8*)(a2 + (sbase + l15) * 72 + 32 + l4 * 8);
            bf16x8 b20 = *(const bf16x8*)(wb + (sbase + l15) * 72 + l4 * 8);
            bf16x8 b21 = *(const bf16x8*)(wb + (sbase + l15) * 72 + 32 + l4 * 8);
            #pragma unroll
            for (int dt = 0; dt < 4; ++dt) {
                int drow = (w * 4 + dt) * 16 + l15;
                bf16x8 a10 = *(const bf16x8*)(tokT + drow * 64 + l4 * 8);
                bf16x8 a11 = *(const bf16x8*)(tokT + drow * 64 + 32 + l4 * 8);
                bf16x8 a20 = *(const bf16x8*)(lds + drow * 80 + l4 * 16);
                bf16x8 a21 = *(const bf16x8*)(lds + drow * 80 + 64 + l4 * 16);
                f32x4 a = {0.f,0.f,0.f,0.f};
                a = MFMA16(a10, b10, a, 0, 0, 0);
                a = MFMA16(a11, b11, a, 0, 0, 0);
                a = MFMA16(a20, b20, a, 0, 0, 0);
                a = MFMA16(a21, b21, a, 0, 0, 0);
                acc[st][dt] = a;
            }
        }
        // xc = x + gav*xres (x from global xT) ; per-s partials (pre-reduced per wave)
        float rs_[3] = {0.f,0.f,0.f}, rq_[3] = {0.f,0.f,0.f};
        #pragma unroll
        for (int st = 0; st < 3; ++st) {
            int s = st * 16 + l15;
            if (s < T_) {
                #pragma unroll
                for (int dt = 0; dt < 4; ++dt) {
                    #pragma unroll
                    for (int j = 0; j < 4; ++j) {
                        int d = (w * 4 + dt) * 16 + l4 * 4 + j;
                        float xsv = bf2f(xTb[s * 512 + d]);
                        float v = xsv + gav * acc[st][dt][j];
                        acc[st][dt][j] = v;
                        rs_[st] += v; rq_[st] += v * v;
                    }
                }
            }
            rs_[st] += __shfl_xor(rs_[st], 16); rq_[st] += __shfl_xor(rq_[st], 16);
            rs_[st] += __shfl_xor(rs_[st], 32); rq_[st] += __shfl_xor(rq_[st], 32);
            if (s < T_ && l4 == 0) {
                red[w * 40 + s] = rs_[st];
                red[320 + w * 40 + s] = rq_[st];
            }
        }
        __syncthreads();
        if (tid < T_) {
            float S = 0.f, Q = 0.f;
            #pragma unroll
            for (int q = 0; q < 8; ++q) { S += red[q * 40 + tid]; Q += red[320 + q * 40 + tid]; }
            float mu = S * (1.f / 512.f);
            float var = Q * (1.f / 512.f) - mu * mu;
            red[640 + tid] = mu; red[680 + tid] = rsqrtf(var + EPS_);
        }
        __syncthreads();
        // h (LN output) -> R0 image [48][1024B] swz (ynat/a2 dead)
        #pragma unroll
        for (int st = 0; st < 3; ++st) {
            int s = st * 16 + l15;
            if (s < T_) {
                float mu = red[640 + s], rsg = red[680 + s];
                #pragma unroll
                for (int dt = 0; dt < 4; ++dt) {
                    #pragma unroll
                    for (int j = 0; j < 4; ++j) {
                        int d = (w * 4 + dt) * 16 + l4 * 4 + j;
                        *(unsigned short*)(lds + swz(s, d)) =
                            f2bf((acc[st][dt][j] - mu) * rsg * lnbg[d] + lnbb[d]);
                    }
                }
            }
        }
    }
    __syncthreads();

    // ---- P7: grouped down conv via MFMA: z[o][s] = wdd(blockdiag) @ h ----
    if (w < 6) {
        int mt = w / 3, nt = w % 3;
        int orow = mt * 16 + l15, srow = nt * 16 + l15;
        f32x4 acc0 = {0.f,0.f,0.f,0.f}, acc1 = {0.f,0.f,0.f,0.f};
        #pragma unroll
        for (int ks = 0; ks < 16; ks += 2) {
            int ka = ks * 32 + l4 * 8, kb = ka + 32;
            acc0 = MFMA16(*(const bf16x8*)(wdd + orow * 512 + ka),
                          *(const bf16x8*)(lds + swz(srow, ka)), acc0, 0, 0, 0);
            acc1 = MFMA16(*(const bf16x8*)(wdd + orow * 512 + kb),
                          *(const bf16x8*)(lds + swz(srow, kb)), acc1, 0, 0, 0);
        }
        f32x4 acc = acc0 + acc1;
        if (srow < T_) {
            #pragma unroll
            for (int j = 0; j < 4; ++j)
                z_pre[b * (DS_ * T_) + (mt * 16 + l4 * 4 + j) * T_ + srow] = acc[j];
        }
    }
}

// ---- K3: bn1 stats, two-level ----
__global__ __launch_bounds__(256)
void k3a_bn1part(const float* __restrict__ z_pre, float* __restrict__ p3)
{
    __shared__ float rbuf[4][2];
    int blk = blockIdx.x;
    int o = blk & 31, sl = blk >> 5;
    int tid = threadIdx.x;
    float S = 0.f, Q = 0.f;
    for (int i = tid; i < 64 * T_; i += 256) {
        int bb = sl * 64 + i / T_, t = i - (i / T_) * T_;
        float v = z_pre[bb * (DS_ * T_) + o * T_ + t];
        S += v; Q += v * v;
    }
    #pragma unroll
    for (int off = 1; off < 64; off <<= 1) { S += __shfl_xor(S, off); Q += __shfl_xor(Q, off); }
    int ww = tid >> 6;
    if ((tid & 63) == 0) { rbuf[ww][0] = S; rbuf[ww][1] = Q; }
    __syncthreads();
    if (tid == 0) {
        float s2 = 0.f, q2 = 0.f;
        for (int i = 0; i < 4; ++i) { s2 += rbuf[i][0]; q2 += rbuf[i][1]; }
        p3[blk * 2] = s2; p3[blk * 2 + 1] = q2;
    }
}

__global__ __launch_bounds__(64)
void k3b_bn1stats(const float* __restrict__ p3, float* __restrict__ st1)
{
    int o = threadIdx.x;
    if (o < 32) {
        float S = 0.f, Q = 0.f;
        for (int sl = 0; sl < 16; ++sl) {
            S += p3[((sl << 5) | o) * 2];
            Q += p3[((sl << 5) | o) * 2 + 1];
        }
        float mu = S / 36864.f;
        float var = Q / 36864.f - mu * mu;
        st1[o] = mu; st1[32 + o] = rsqrtf(var + EPS_);
    }
}

// ---- K4M: per-group 8x8 second-moment partials of zr = relu(bn1(z)) ----
__global__ __launch_bounds__(256)
void k4m_moments(const float* __restrict__ z_pre, const float* __restrict__ st1,
                 const float* __restrict__ g1p, const float* __restrict__ b1p,
                 float* __restrict__ m4)
{
    __shared__ float zr[32][40];
    int blk = blockIdx.x, tid = threadIdx.x;
    int c2 = tid & 7, c1 = (tid >> 3) & 7, g = tid >> 6;
    int ch1 = g * 8 + c1, ch2 = g * 8 + c2;
    float acc = 0.f, asum = 0.f;
    for (int bi = 0; bi < 8; ++bi) {
        int b = blk * 8 + bi;
        __syncthreads();
        for (int i = tid; i < DS_ * T_; i += 256) {
            int o = i / T_, t = i - o * T_;
            float v = z_pre[b * (DS_ * T_) + i];
            zr[o][t] = fmaxf(0.f, (v - st1[o]) * st1[32 + o] * g1p[o] + b1p[o]);
        }
        __syncthreads();
        for (int t = 0; t < T_; ++t) {
            float a = zr[ch1][t], b2 = zr[ch2][t];
            acc += a * b2;
            asum += a;
        }
    }
    m4[blk * 288 + tid] = acc;
    if (c1 == c2) m4[blk * 288 + 256 + g * 8 + c1] = asum;
}

// ---- K4S: reduce moments -> bn2 stats via E[o^2] = w^T M w ----
__global__ __launch_bounds__(512)
void k4s_bn2stats(const float* __restrict__ m4, const float* __restrict__ wu,
                  float* __restrict__ st2)
{
    __shared__ float M2[256], mz[32];
    int tid = threadIdx.x;
    if (tid < 256) {
        float S = 0.f;
        for (int k = 0; k < 128; ++k) S += m4[k * 288 + tid];
        M2[tid] = S * (1.f / 36864.f);
    } else if (tid < 288) {
        int j = tid - 256;
        float S = 0.f;
        for (int k = 0; k < 128; ++k) S += m4[k * 288 + 256 + j];
        mz[j] = S * (1.f / 36864.f);
    }
    __syncthreads();
    int d = tid, g = d >> 7;
    float wr[8];
    #pragma unroll
    for (int c = 0; c < 8; ++c) wr[c] = wu[d * 8 + c];
    float mu2 = 0.f;
    #pragma unroll
    for (int c = 0; c < 8; ++c) mu2 += wr[c] * mz[g * 8 + c];
    float e2 = 0.f;
    #pragma unroll
    for (int c = 0; c < 8; ++c)
        #pragma unroll
        for (int c2 = 0; c2 < 8; ++c2)
            e2 += wr[c] * wr[c2] * M2[g * 64 + c * 8 + c2];
    st2[d] = mu2;
    st2[512 + d] = rsqrtf(e2 - mu2 * mu2 + EPS_);
}

// ---- K5: up conv + bn2 + LN(lnp) + gate -> out ----
#define K5_LDS 47888
__global__ __launch_bounds__(512, 6)
void k5_final(const float* __restrict__ z_pre, const float* __restrict__ st1,
              const float* __restrict__ g1p, const float* __restrict__ b1p,
              const float* __restrict__ wu, const float* __restrict__ st2,
              const float* __restrict__ g2p, const float* __restrict__ b2p,
              const float* __restrict__ lnpg, const float* __restrict__ lnpb,
              const float* __restrict__ gate_p, float* __restrict__ out)
{
    extern __shared__ char lds[];
    unsigned short* o_f = (unsigned short*)lds;   // [512][41]
    float* zrT = (float*)(lds + 41984);           // [36][41]
    int b = blockIdx.x;
    int tid = threadIdx.x;

    for (int i = tid; i < DS_ * T_; i += 512) {
        int o = i / T_, s = i - o * T_;
        float v = z_pre[b * (DS_ * T_) + i];
        zrT[s * 41 + o] = fmaxf(0.f, (v - st1[o]) * st1[32 + o] * g1p[o] + b1p[o]);
    }
    __syncthreads();

    for (int i = tid; i < D_ * T_; i += 512) {
        int d = i / T_, t = i - d * T_;
        const float* zp = &zrT[t * 41 + (d >> 7) * 8];
        const float* wp = &wu[d * 8];
        f32x4 w0 = *(const f32x4*)wp;
        f32x4 w1 = *(const f32x4*)(wp + 4);
        float acc = zp[0]*w0[0] + zp[1]*w0[1] + zp[2]*w0[2] + zp[3]*w0[3]
                  + zp[4]*w1[0] + zp[5]*w1[1] + zp[6]*w1[2] + zp[7]*w1[3];
        o_f[d * 41 + t] = f2bf((acc - st2[d]) * st2[512 + d] * g2p[d] + b2p[d]);
    }
    __syncthreads();

    int w = tid >> 6, lane = tid & 63;
    float gate = gate_p[0];
    for (int t = w; t < T_; t += 8) {
        float S = 0.f, Q = 0.f;
        float v[8];
        #pragma unroll
        for (int i2 = 0; i2 < 8; ++i2) {
            float vv = bf2f(o_f[(i2 * 64 + lane) * 41 + t]);
            v[i2] = vv; S += vv; Q += vv * vv;
        }
        #pragma unroll
        for (int off = 1; off < 64; off <<= 1) { S += __shfl_xor(S, off); Q += __shfl_xor(Q, off); }
        float mu = S * (1.f / 512.f);
        float var = Q * (1.f / 512.f) - mu * mu;
        float rs = rsqrtf(var + EPS_);
        #pragma unroll
        for (int i2 = 0; i2 < 8; ++i2) {
            int d = i2 * 64 + lane;
            o_f[d * 41 + t] = f2bf(gate * ((v[i2] - mu) * rs * lnpg[d] + lnpb[d]));
        }
    }
    __syncthreads();

    float* ob = out + b * (D_ * T_);
    for (int i = tid; i < D_ * T_; i += 512) {
        int d = i / T_, t = i - d * T_;
        ob[i] = bf2f(o_f[d * 41 + t]);
    }
}

extern "C" void kernel_launch(void* const* d_in, const int* in_sizes, int n_in,
                              void* d_out, int out_size, void* d_ws, size_t ws_size,
                              hipStream_t stream)
{
    (void)in_sizes; (void)n_in; (void)out_size;
    const float* x    = (const float*)d_in[0];
    const float* y    = (const float*)d_in[1];
    const float* tok  = (const float*)d_in[2];
    const float* gate = (const float*)d_in[3];
    const float* gav  = (const float*)d_in[4];
    const float* wd   = (const float*)d_in[5];
    const float* wu   = (const float*)d_in[6];
    const float* bn1g = (const float*)d_in[7];
    const float* bn1b = (const float*)d_in[8];
    const float* bn2g = (const float*)d_in[9];
    const float* bn2b = (const float*)d_in[10];
    const float* lnbg = (const float*)d_in[11];
    const float* lnbb = (const float*)d_in[12];
    const float* lnpg = (const float*)d_in[13];
    const float* lnpb = (const float*)d_in[14];
    float* out = (float*)d_out;

    char* ws = (char*)d_ws;
    float* z_pre          = (float*)ws;                      // 4,718,592
    float* st1            = (float*)(ws + 4718592);          // 512
    unsigned short* tokbf = (unsigned short*)(ws + 4719104); // 65,536
    unsigned short* tokT  = (unsigned short*)(ws + 4784640); // 65,536
    unsigned short* wdd   = (unsigned short*)(ws + 4850176); // 32,768
    float* p3             = (float*)(ws + 4882944);          // 4,096
    float* m4             = (float*)(ws + 4887040);          // 147,456
    float* st2            = (float*)(ws + 5034496);          // 4,096
    unsigned short* xT    = (unsigned short*)(ws + 5038592); // chunk * 49,152

    size_t avail = (ws_size > 5038592) ? (ws_size - 5038592) : 49152;
    int chunk = (int)(avail / 49152);
    if (chunk < 1) chunk = 1;
    if (chunk > B_) chunk = B_;

    hipFuncSetAttribute((const void*)k1_fused, hipFuncAttributeMaxDynamicSharedMemorySize, K1_LDS);
    hipFuncSetAttribute((const void*)k5_final, hipFuncAttributeMaxDynamicSharedMemorySize, K5_LDS);

    k0_prepack<<<160, 512, 0, stream>>>(tok, wd, tokbf, tokT, wdd);
    for (int b0 = 0; b0 < B_; b0 += chunk) {
        int cnt = (b0 + chunk <= B_) ? chunk : (B_ - b0);
        kA_xpose<<<cnt, 512, 0, stream>>>(x, xT, b0);
        k1_fused<<<cnt, 512, K1_LDS, stream>>>(xT, y, tokbf, tokT, gav, wdd, lnbg, lnbb, z_pre, b0);
    }
    k3a_bn1part<<<512, 256, 0, stream>>>(z_pre, p3);
    k3b_bn1stats<<<1, 64, 0, stream>>>(p3, st1);
    k4m_moments<<<128, 256, 0, stream>>>(z_pre, st1, bn1g, bn1b, m4);
    k4s_bn2stats<<<1, 512, 0, stream>>>(m4, wu, st2);
    k5_final<<<B_, 512, K5_LDS, stream>>>(z_pre, st1, bn1g, bn1b, wu, st2, bn2g, bn2b,
                                          lnpg, lnpb, gate, out);
}

// Round 9
// 199.424 us; speedup vs baseline: 1.2306x; 1.2306x over previous
//
#include <hip/hip_runtime.h>

#define B_ 1024
#define D_ 512
#define T_ 36
#define NT_ 64
#define DS_ 32
#define EPS_ 1e-5f

typedef float f32x4 __attribute__((ext_vector_type(4)));
typedef __bf16 bf16x8 __attribute__((ext_vector_type(8)));
typedef unsigned short u16x8 __attribute__((ext_vector_type(8)));
typedef unsigned short u16x4 __attribute__((ext_vector_type(4)));

#define DEVI static __device__ __forceinline__
#define MFMA16 __builtin_amdgcn_mfma_f32_16x16x32_bf16

DEVI unsigned short f2bf(float f) { return __builtin_bit_cast(unsigned short, (__bf16)f); }
DEVI float bf2f(unsigned short h) { return (float)__builtin_bit_cast(__bf16, h); }

// XOR-swizzled byte offset inside a [48 rows][1024B] transposed image (T2)
DEVI unsigned swz(int row, int col) {   // col in ushort elements (0..511)
    return (unsigned)(row * 1024 + ((2 * col) ^ ((row & 7) << 4)));
}

// ---- 4-deep software-pipelined K=512 tile: A row from global, B from swz image ----
DEVI f32x4 tile16_gl(const unsigned short* __restrict__ Arow, const char* img, int brow, int l4)
{
    bf16x8 Ar[4], Br[4];
    #pragma unroll
    for (int p = 0; p < 4; ++p) {
        int k0 = p * 32 + l4 * 8;
        Ar[p] = *(const bf16x8*)(Arow + k0);
        Br[p] = *(const bf16x8*)(img + swz(brow, k0));
    }
    f32x4 acc = {0.f, 0.f, 0.f, 0.f};
    #pragma unroll
    for (int ks = 0; ks < 16; ++ks) {
        bf16x8 a = Ar[ks & 3], bv = Br[ks & 3];
        if (ks < 12) {
            int k0 = (ks + 4) * 32 + l4 * 8;
            Ar[ks & 3] = *(const bf16x8*)(Arow + k0);
            Br[ks & 3] = *(const bf16x8*)(img + swz(brow, k0));
        }
        acc = MFMA16(a, bv, acc, 0, 0, 0);
    }
    return acc;
}

// ---- same, A also from a swizzled LDS image ----
DEVI f32x4 tile16_ll(const char* imgA, int arow, const char* imgB, int brow, int l4)
{
    bf16x8 Ar[4], Br[4];
    #pragma unroll
    for (int p = 0; p < 4; ++p) {
        int k0 = p * 32 + l4 * 8;
        Ar[p] = *(const bf16x8*)(imgA + swz(arow, k0));
        Br[p] = *(const bf16x8*)(imgB + swz(brow, k0));
    }
    f32x4 acc = {0.f, 0.f, 0.f, 0.f};
    #pragma unroll
    for (int ks = 0; ks < 16; ++ks) {
        bf16x8 a = Ar[ks & 3], bv = Br[ks & 3];
        if (ks < 12) {
            int k0 = (ks + 4) * 32 + l4 * 8;
            Ar[ks & 3] = *(const bf16x8*)(imgA + swz(arow, k0));
            Br[ks & 3] = *(const bf16x8*)(imgB + swz(brow, k0));
        }
        acc = MFMA16(a, bv, acc, 0, 0, 0);
    }
    return acc;
}

// ---- K1 LDS layout ----
// R0 @0: ysT [48][1024B] swz (49,152) -> ynat/repT [512][144B] overlay (73,728)
// XST @73,728: xsT [48][1024B] swz (49,152)   (h_sT overlay after LN)
// SC  @122,880: sc f32 [64][42] (10,752)       (red overlay in epilogue)
// A1  @133,632: att1 u16 [64][72] (9,216)
// A2  @142,848: att2 u16 [48][72] (6,912)
// GT  @149,760: GramT u16 [48][72] (6,912)
#define OFF_XST 73728
#define OFF_SC  122880
#define OFF_A1  133632
#define OFF_A2  142848
#define OFF_GT  149760
#define K1_LDS  156672

// ---- K0: prepack tok bf16 [64][512], tokT f32 [512][64], block-diag wd bf16 [32][512] ----
__global__ __launch_bounds__(512)
void k0_prepack(const float* __restrict__ tok, const float* __restrict__ wd,
                unsigned short* __restrict__ tokbf, float* __restrict__ tokTf,
                unsigned short* __restrict__ wdd)
{
    int i = blockIdx.x * 512 + threadIdx.x;
    if (i < 32768) {
        tokbf[i] = f2bf(tok[i]);
    } else if (i < 65536) {
        int j = i - 32768; int d = j >> 6, t = j & 63;
        tokTf[j] = tok[t * 512 + d];
    } else if (i < 81920) {
        int j = i - 65536; int o = j >> 9, dd = j & 511;
        wdd[j] = ((dd >> 7) == (o >> 3)) ? f2bf(wd[o * 128 + (dd & 127)]) : (unsigned short)0;
    }
}

// =================== K1: fused attention + LN + downconv (pipelined K-loops) ===================
__global__ __launch_bounds__(1024, 4)
void k1_fused(const float* __restrict__ x, const float* __restrict__ y,
              const unsigned short* __restrict__ tokbf, const float* __restrict__ tokTf,
              const float* __restrict__ gav_p, const unsigned short* __restrict__ wdd,
              const float* __restrict__ lnbg, const float* __restrict__ lnbb,
              float* __restrict__ z_pre)
{
    extern __shared__ char lds[];
    float* sc = (float*)(lds + OFF_SC);
    unsigned short* a1 = (unsigned short*)(lds + OFF_A1);
    unsigned short* a2 = (unsigned short*)(lds + OFF_A2);
    unsigned short* gt = (unsigned short*)(lds + OFF_GT);

    const int b    = blockIdx.x;
    const int tid  = threadIdx.x;
    const int lane = tid & 63;
    const int w    = tid >> 6;   // 0..15
    const int l15  = lane & 15;
    const int l4   = lane >> 4;  // 0..3

    const float* yb = y + b * (D_ * T_);
    const float* xb = x + b * (D_ * T_);

    // ---- P0: zero pads ----
    {
        unsigned* z1 = (unsigned*)(lds + 36 * 1024);
        unsigned* z2 = (unsigned*)(lds + OFF_XST + 36 * 1024);
        for (int i = tid; i < 3072; i += 1024) { z1[i] = 0u; z2[i] = 0u; }
        unsigned* z3 = (unsigned*)(lds + OFF_A1);   // a1+a2+gt contiguous: 23,040 B
        for (int i = tid; i < 5760; i += 1024) z3[i] = 0u;
    }
    // ---- stage ysT and xsT (transposed, swizzled, vectorized) ----
    for (int ww = tid; ww < 1152; ww += 1024) {
        int isx = (ww >= 576) ? 1 : 0;
        int u = isx ? (ww - 576) : ww;
        const float* src = isx ? xb : yb;
        char* dst = lds + (isx ? OFF_XST : 0);
        int dblk = u / 9, s4 = u - dblk * 9;
        int s0 = s4 * 4;
        const float* bp = src + dblk * 8 * T_ + s0;
        u16x8 u0, u1, u2, u3;
        #pragma unroll
        for (int r = 0; r < 8; ++r) {
            f32x4 v = *(const f32x4*)(bp + r * T_);
            u0[r] = f2bf(v[0]); u1[r] = f2bf(v[1]);
            u2[r] = f2bf(v[2]); u3[r] = f2bf(v[3]);
        }
        *(u16x8*)(dst + swz(s0 + 0, dblk * 8)) = u0;
        *(u16x8*)(dst + swz(s0 + 1, dblk * 8)) = u1;
        *(u16x8*)(dst + swz(s0 + 2, dblk * 8)) = u2;
        *(u16x8*)(dst + swz(s0 + 3, dblk * 8)) = u3;
    }
    __syncthreads();

    // ---- P1: G1 (S1 = tok@y, 12 tiles) + GramT (x^T y, 9 tiles), pipelined ----
    for (int tile = w; tile < 21; tile += 16) {
        if (tile < 12) {
            int mt = tile / 3, nt = tile % 3;
            int trow = mt * 16 + l15, srow = nt * 16 + l15;
            f32x4 acc = tile16_gl(tokbf + trow * 512, lds, srow, l4);
            if (srow < T_) {
                #pragma unroll
                for (int j = 0; j < 4; ++j)
                    sc[(mt * 16 + l4 * 4 + j) * 42 + srow] = acc[j];
            }
        } else {
            int g2 = tile - 12;
            int mt = g2 / 3, nt = g2 % 3;
            int arow = mt * 16 + l15, brow = nt * 16 + l15;
            f32x4 acc = tile16_ll(lds + OFF_XST, arow, lds, brow, l4);
            #pragma unroll
            for (int j = 0; j < 4; ++j) {
                int gr = mt * 16 + l4 * 4 + j;
                if (gr < T_) gt[gr * 72 + brow] = f2bf(acc[j]);
            }
        }
    }
    __syncthreads();

    // ---- sm1 (softmax over s per t -> att1) || restage y native bf16 into region0 ----
    {
        int t = tid >> 4, l16 = tid & 15;
        const float* scp = sc + t * 42;
        float v0 = scp[l16];
        float v1 = scp[l16 + 16];
        float v2 = (l16 < 4) ? scp[l16 + 32] : -1e30f;
        float m = fmaxf(fmaxf(v0, v1), v2);
        #pragma unroll
        for (int off = 1; off < 16; off <<= 1) m = fmaxf(m, __shfl_xor(m, off));
        float e0 = __expf(v0 - m), e1 = __expf(v1 - m);
        float e2 = (l16 < 4) ? __expf(v2 - m) : 0.f;
        float ssum = e0 + e1 + e2;
        #pragma unroll
        for (int off = 1; off < 16; off <<= 1) ssum += __shfl_xor(ssum, off);
        float inv = 1.f / ssum;
        a1[t * 72 + l16]      = f2bf(e0 * inv);
        a1[t * 72 + l16 + 16] = f2bf(e1 * inv);
        if (l16 < 4) a1[t * 72 + l16 + 32] = f2bf(e2 * inv);
    }
    // ynat[d][s] bf16 at row d*144, cols 0..35; cols 36..63 zeroed (K-pad NaN safety)
    for (int j = tid; j < 4608; j += 1024) {
        int row = j / 9, q = j - row * 9;
        f32x4 v = *(const f32x4*)(yb + row * T_ + q * 4);
        u16x4 hh;
        #pragma unroll
        for (int jj = 0; jj < 4; ++jj) hh[jj] = f2bf(v[jj]);
        *(u16x4*)(lds + row * 144 + q * 8) = hh;
    }
    if (tid < 512) {
        char* p = lds + tid * 144;
        u16x4 z4 = {0,0,0,0}; u16x8 z8 = {0,0,0,0,0,0,0,0};
        *(u16x4*)(p + 72) = z4;
        *(u16x8*)(p + 80) = z8;
        *(u16x8*)(p + 96) = z8;
        *(u16x8*)(p + 112) = z8;
    }
    __syncthreads();

    // ---- G2 (in-place: repT[d][t] = tok[t][d] + sum_s ynat[d][s] att1[t][s]) || P3 ----
    {
        #pragma unroll
        for (int half = 0; half < 2; ++half) {
            int dbase = (w + 16 * half) * 16;
            bf16x8 fa0 = *(const bf16x8*)(lds + (dbase + l15) * 144 + l4 * 16);
            bf16x8 fa1 = *(const bf16x8*)(lds + (dbase + l15) * 144 + 64 + l4 * 16);
            bf16x8 fb0[4], fb1[4];
            #pragma unroll
            for (int tt = 0; tt < 4; ++tt) {
                fb0[tt] = *(const bf16x8*)(a1 + (tt * 16 + l15) * 72 + l4 * 8);
                fb1[tt] = *(const bf16x8*)(a1 + (tt * 16 + l15) * 72 + 32 + l4 * 8);
            }
            float tv[16];
            #pragma unroll
            for (int tt = 0; tt < 4; ++tt)
                #pragma unroll
                for (int j = 0; j < 4; ++j)
                    tv[tt * 4 + j] = tokTf[(dbase + l4 * 4 + j) * 64 + tt * 16 + l15];
            f32x4 c[4];
            #pragma unroll
            for (int tt = 0; tt < 4; ++tt) {
                f32x4 acc = {0.f,0.f,0.f,0.f};
                acc = MFMA16(fa0, fb0[tt], acc, 0, 0, 0);
                acc = MFMA16(fa1, fb1[tt], acc, 0, 0, 0);
                c[tt] = acc;
            }
            // all reads of these rows complete (per-wave private rows) -> write rep
            #pragma unroll
            for (int tt = 0; tt < 4; ++tt) {
                #pragma unroll
                for (int j = 0; j < 4; ++j) {
                    int d = dbase + l4 * 4 + j;
                    *(unsigned short*)(lds + d * 144 + 2 * (tt * 16 + l15)) =
                        f2bf(tv[tt * 4 + j] + c[tt][j]);
                }
            }
        }
    }
    // P3: sc[t][s] = tok@x (K=512, pipelined) + a1@gt^T (K=36 pad 64); 12 tiles
    if (w < 12) {
        int mt = w / 3, nt = w % 3;
        int trow = mt * 16 + l15, srow = nt * 16 + l15;
        // small-K fragments preloaded up front
        bf16x8 sa0 = *(const bf16x8*)(a1 + trow * 72 + l4 * 8);
        bf16x8 sa1 = *(const bf16x8*)(a1 + trow * 72 + 32 + l4 * 8);
        bf16x8 sb0 = *(const bf16x8*)(gt + srow * 72 + l4 * 8);
        bf16x8 sb1 = *(const bf16x8*)(gt + srow * 72 + 32 + l4 * 8);
        f32x4 acc = tile16_gl(tokbf + trow * 512, lds + OFF_XST, srow, l4);
        acc = MFMA16(sa0, sb0, acc, 0, 0, 0);
        acc = MFMA16(sa1, sb1, acc, 0, 0, 0);
        if (srow < T_) {
            #pragma unroll
            for (int j = 0; j < 4; ++j)
                sc[(mt * 16 + l4 * 4 + j) * 42 + srow] = acc[j];
        }
    }
    __syncthreads();

    // ---- sm2: softmax over t per s -> att2 [s][t] ----
    if (tid < 576) {
        int s = tid >> 4, l16 = tid & 15;
        float v0 = sc[(l16     ) * 42 + s];
        float v1 = sc[(l16 + 16) * 42 + s];
        float v2 = sc[(l16 + 32) * 42 + s];
        float v3 = sc[(l16 + 48) * 42 + s];
        float m = fmaxf(fmaxf(v0, v1), fmaxf(v2, v3));
        #pragma unroll
        for (int off = 1; off < 16; off <<= 1) m = fmaxf(m, __shfl_xor(m, off));
        float e0 = __expf(v0 - m), e1 = __expf(v1 - m), e2 = __expf(v2 - m), e3 = __expf(v3 - m);
        float ssum = e0 + e1 + e2 + e3;
        #pragma unroll
        for (int off = 1; off < 16; off <<= 1) ssum += __shfl_xor(ssum, off);
        float inv = 1.f / ssum;
        a2[s * 72 + l16]      = f2bf(e0 * inv);
        a2[s * 72 + l16 + 16] = f2bf(e1 * inv);
        a2[s * 72 + l16 + 32] = f2bf(e2 * inv);
        a2[s * 72 + l16 + 48] = f2bf(e3 * inv);
    }
    __syncthreads();

    // ---- P6: xresT[d][s] = repT @ att2^T (96 tiles, 6/wave, ping-pong pipelined) ; xc ; LN ----
    {
        const float gav = gav_p[0];
        float* red = sc;   // overlay dead sc
        f32x4 acc6[6];
        bf16x8 pa[2][2], pb[2][2];
        {
            int q0 = w * 6;
            int dbase = (q0 & 31) * 16, sbase = (q0 >> 5) * 16;
            #pragma unroll
            for (int ks = 0; ks < 2; ++ks) {
                pa[0][ks] = *(const bf16x8*)(lds + (dbase + l15) * 144 + (ks * 32 + l4 * 8) * 2);
                pb[0][ks] = *(const bf16x8*)(a2 + (sbase + l15) * 72 + ks * 32 + l4 * 8);
            }
        }
        #pragma unroll
        for (int i = 0; i < 6; ++i) {
            int cur = i & 1, nxt = cur ^ 1;
            if (i < 5) {
                int q = w * 6 + i + 1;
                int dbase = (q & 31) * 16, sbase = (q >> 5) * 16;
                #pragma unroll
                for (int ks = 0; ks < 2; ++ks) {
                    pa[nxt][ks] = *(const bf16x8*)(lds + (dbase + l15) * 144 + (ks * 32 + l4 * 8) * 2);
                    pb[nxt][ks] = *(const bf16x8*)(a2 + (sbase + l15) * 72 + ks * 32 + l4 * 8);
                }
            }
            f32x4 acc = {0.f,0.f,0.f,0.f};
            acc = MFMA16(pa[cur][0], pb[cur][0], acc, 0, 0, 0);
            acc = MFMA16(pa[cur][1], pb[cur][1], acc, 0, 0, 0);
            acc6[i] = acc;
        }
        // xc + per-s partial sums
        #pragma unroll
        for (int i = 0; i < 6; ++i) {
            int q = w * 6 + i;
            int dt = q & 31, st = q >> 5;
            int dbase = dt * 16, sbase = st * 16;
            int s = sbase + l15;
            float rsum = 0.f, rsq = 0.f;
            if (s < T_) {
                #pragma unroll
                for (int j = 0; j < 4; ++j) {
                    int d = dbase + l4 * 4 + j;
                    float xsv = bf2f(*(const unsigned short*)(lds + OFF_XST + swz(s, d)));
                    float v = xsv + gav * acc6[i][j];
                    acc6[i][j] = v;
                    rsum += v; rsq += v * v;
                }
            }
            rsum += __shfl_xor(rsum, 16); rsq += __shfl_xor(rsq, 16);
            rsum += __shfl_xor(rsum, 32); rsq += __shfl_xor(rsq, 32);
            if (s < T_ && l4 == 0) {
                red[dt * 40 + s] = rsum;
                red[1280 + dt * 40 + s] = rsq;
            }
        }
        __syncthreads();
        if (tid < T_) {
            int s = tid; float S = 0.f, Q = 0.f;
            #pragma unroll
            for (int q = 0; q < 32; ++q) { S += red[q * 40 + s]; Q += red[1280 + q * 40 + s]; }
            float mu = S * (1.f / 512.f);
            float var = Q * (1.f / 512.f) - mu * mu;
            red[2560 + s] = mu; red[2600 + s] = rsqrtf(var + EPS_);
        }
        __syncthreads();
        // h (LN output) overlays xsT rows 0..35 (pad rows stay zero for P7)
        #pragma unroll
        for (int i = 0; i < 6; ++i) {
            int q = w * 6 + i;
            int dt = q & 31, st = q >> 5;
            int dbase = dt * 16, sbase = st * 16;
            int s = sbase + l15;
            if (s < T_) {
                float mu = red[2560 + s], rsig = red[2600 + s];
                #pragma unroll
                for (int j = 0; j < 4; ++j) {
                    int d = dbase + l4 * 4 + j;
                    float g = lnbg[d], bb2 = lnbb[d];
                    *(unsigned short*)(lds + OFF_XST + swz(s, d)) =
                        f2bf((acc6[i][j] - mu) * rsig * g + bb2);
                }
            }
        }
    }
    __syncthreads();

    // ---- P7: grouped down conv via MFMA: z[o][s] = wdd(blockdiag) @ h (pipelined) ----
    if (w < 6) {
        int mt = w / 3, nt = w % 3;
        int orow = mt * 16 + l15, srow = nt * 16 + l15;
        f32x4 acc = tile16_gl(wdd + orow * 512, lds + OFF_XST, srow, l4);
        if (srow < T_) {
            #pragma unroll
            for (int j = 0; j < 4; ++j)
                z_pre[b * (DS_ * T_) + (mt * 16 + l4 * 4 + j) * T_ + srow] = acc[j];
        }
    }
}

// ---- K3: bn1 stats, two-level ----
__global__ __launch_bounds__(256)
void k3a_bn1part(const float* __restrict__ z_pre, float* __restrict__ p3)
{
    __shared__ float rbuf[4][2];
    int blk = blockIdx.x;
    int o = blk & 31, sl = blk >> 5;
    int tid = threadIdx.x;
    float S = 0.f, Q = 0.f;
    for (int i = tid; i < 64 * T_; i += 256) {
        int bb = sl * 64 + i / T_, t = i - (i / T_) * T_;
        float v = z_pre[bb * (DS_ * T_) + o * T_ + t];
        S += v; Q += v * v;
    }
    #pragma unroll
    for (int off = 1; off < 64; off <<= 1) { S += __shfl_xor(S, off); Q += __shfl_xor(Q, off); }
    int ww = tid >> 6;
    if ((tid & 63) == 0) { rbuf[ww][0] = S; rbuf[ww][1] = Q; }
    __syncthreads();
    if (tid == 0) {
        float s2 = 0.f, q2 = 0.f;
        for (int i = 0; i < 4; ++i) { s2 += rbuf[i][0]; q2 += rbuf[i][1]; }
        p3[blk * 2] = s2; p3[blk * 2 + 1] = q2;
    }
}

__global__ __launch_bounds__(64)
void k3b_bn1stats(const float* __restrict__ p3, float* __restrict__ st1)
{
    int o = threadIdx.x;
    if (o < 32) {
        float S = 0.f, Q = 0.f;
        for (int sl = 0; sl < 16; ++sl) {
            S += p3[((sl << 5) | o) * 2];
            Q += p3[((sl << 5) | o) * 2 + 1];
        }
        float mu = S / 36864.f;
        float var = Q / 36864.f - mu * mu;
        st1[o] = mu; st1[32 + o] = rsqrtf(var + EPS_);
    }
}

// ---- K4M: per-group 8x8 second-moment partials of zr = relu(bn1(z)) ----
__global__ __launch_bounds__(256)
void k4m_moments(const float* __restrict__ z_pre, const float* __restrict__ st1,
                 const float* __restrict__ g1p, const float* __restrict__ b1p,
                 float* __restrict__ m4)
{
    __shared__ float zr[32][40];
    int blk = blockIdx.x, tid = threadIdx.x;
    int c2 = tid & 7, c1 = (tid >> 3) & 7, g = tid >> 6;
    int ch1 = g * 8 + c1, ch2 = g * 8 + c2;
    float acc = 0.f, asum = 0.f;
    for (int bi = 0; bi < 8; ++bi) {
        int b = blk * 8 + bi;
        __syncthreads();
        for (int i = tid; i < DS_ * T_; i += 256) {
            int o = i / T_, t = i - o * T_;
            float v = z_pre[b * (DS_ * T_) + i];
            zr[o][t] = fmaxf(0.f, (v - st1[o]) * st1[32 + o] * g1p[o] + b1p[o]);
        }
        __syncthreads();
        for (int t = 0; t < T_; ++t) {
            float a = zr[ch1][t], b2 = zr[ch2][t];
            acc += a * b2;
            asum += a;
        }
    }
    m4[blk * 288 + tid] = acc;
    if (c1 == c2) m4[blk * 288 + 256 + g * 8 + c1] = asum;
}

// ---- K4S: reduce moments -> bn2 stats via E[o^2] = w^T M w ----
__global__ __launch_bounds__(512)
void k4s_bn2stats(const float* __restrict__ m4, const float* __restrict__ wu,
                  float* __restrict__ st2)
{
    __shared__ float M2[256], mz[32];
    int tid = threadIdx.x;
    if (tid < 256) {
        float S = 0.f;
        for (int k = 0; k < 128; ++k) S += m4[k * 288 + tid];
        M2[tid] = S * (1.f / 36864.f);
    } else if (tid < 288) {
        int j = tid - 256;
        float S = 0.f;
        for (int k = 0; k < 128; ++k) S += m4[k * 288 + 256 + j];
        mz[j] = S * (1.f / 36864.f);
    }
    __syncthreads();
    int d = tid, g = d >> 7;
    float wr[8];
    #pragma unroll
    for (int c = 0; c < 8; ++c) wr[c] = wu[d * 8 + c];
    float mu2 = 0.f;
    #pragma unroll
    for (int c = 0; c < 8; ++c) mu2 += wr[c] * mz[g * 8 + c];
    float e2 = 0.f;
    #pragma unroll
    for (int c = 0; c < 8; ++c)
        #pragma unroll
        for (int c2 = 0; c2 < 8; ++c2)
            e2 += wr[c] * wr[c2] * M2[g * 64 + c * 8 + c2];
    st2[d] = mu2;
    st2[512 + d] = rsqrtf(e2 - mu2 * mu2 + EPS_);
}

// ---- K5: up conv + bn2 + LN(lnp) + gate -> out ----
#define K5_LDS 47888
__global__ __launch_bounds__(512, 6)
void k5_final(const float* __restrict__ z_pre, const float* __restrict__ st1,
              const float* __restrict__ g1p, const float* __restrict__ b1p,
              const float* __restrict__ wu, const float* __restrict__ st2,
              const float* __restrict__ g2p, const float* __restrict__ b2p,
              const float* __restrict__ lnpg, const float* __restrict__ lnpb,
              const float* __restrict__ gate_p, float* __restrict__ out)
{
    extern __shared__ char lds[];
    unsigned short* o_f = (unsigned short*)lds;   // [512][41]
    float* zrT = (float*)(lds + 41984);           // [36][41]
    int b = blockIdx.x;
    int tid = threadIdx.x;

    for (int i = tid; i < DS_ * T_; i += 512) {
        int o = i / T_, s = i - o * T_;
        float v = z_pre[b * (DS_ * T_) + i];
        zrT[s * 41 + o] = fmaxf(0.f, (v - st1[o]) * st1[32 + o] * g1p[o] + b1p[o]);
    }
    __syncthreads();

    for (int i = tid; i < D_ * T_; i += 512) {
        int d = i / T_, t = i - d * T_;
        const float* zp = &zrT[t * 41 + (d >> 7) * 8];
        const float* wp = &wu[d * 8];
        f32x4 w0 = *(const f32x4*)wp;
        f32x4 w1 = *(const f32x4*)(wp + 4);
        float acc = zp[0]*w0[0] + zp[1]*w0[1] + zp[2]*w0[2] + zp[3]*w0[3]
                  + zp[4]*w1[0] + zp[5]*w1[1] + zp[6]*w1[2] + zp[7]*w1[3];
        o_f[d * 41 + t] = f2bf((acc - st2[d]) * st2[512 + d] * g2p[d] + b2p[d]);
    }
    __syncthreads();

    int w = tid >> 6, lane = tid & 63;
    float gate = gate_p[0];
    for (int t = w; t < T_; t += 8) {
        float S = 0.f, Q = 0.f;
        float v[8];
        #pragma unroll
        for (int i2 = 0; i2 < 8; ++i2) {
            float vv = bf2f(o_f[(i2 * 64 + lane) * 41 + t]);
            v[i2] = vv; S += vv; Q += vv * vv;
        }
        #pragma unroll
        for (int off = 1; off < 64; off <<= 1) { S += __shfl_xor(S, off); Q += __shfl_xor(Q, off); }
        float mu = S * (1.f / 512.f);
        float var = Q * (1.f / 512.f) - mu * mu;
        float rs = rsqrtf(var + EPS_);
        #pragma unroll
        for (int i2 = 0; i2 < 8; ++i2) {
            int d = i2 * 64 + lane;
            o_f[d * 41 + t] = f2bf(gate * ((v[i2] - mu) * rs * lnpg[d] + lnpb[d]));
        }
    }
    __syncthreads();

    float* ob = out + b * (D_ * T_);
    for (int i = tid; i < D_ * T_; i += 512) {
        int d = i / T_, t = i - d * T_;
        ob[i] = bf2f(o_f[d * 41 + t]);
    }
}

extern "C" void kernel_launch(void* const* d_in, const int* in_sizes, int n_in,
                              void* d_out, int out_size, void* d_ws, size_t ws_size,
                              hipStream_t stream)
{
    (void)in_sizes; (void)n_in; (void)out_size; (void)ws_size;
    const float* x    = (const float*)d_in[0];
    const float* y    = (const float*)d_in[1];
    const float* tok  = (const float*)d_in[2];
    const float* gate = (const float*)d_in[3];
    const float* gav  = (const float*)d_in[4];
    const float* wd   = (const float*)d_in[5];
    const float* wu   = (const float*)d_in[6];
    const float* bn1g = (const float*)d_in[7];
    const float* bn1b = (const float*)d_in[8];
    const float* bn2g = (const float*)d_in[9];
    const float* bn2b = (const float*)d_in[10];
    const float* lnbg = (const float*)d_in[11];
    const float* lnbb = (const float*)d_in[12];
    const float* lnpg = (const float*)d_in[13];
    const float* lnpb = (const float*)d_in[14];
    float* out = (float*)d_out;

    char* ws = (char*)d_ws;
    float* z_pre          = (float*)ws;                      // 4,718,592
    float* st1            = (float*)(ws + 4718592);          // 512
    unsigned short* tokbf = (unsigned short*)(ws + 4719104); // 65,536
    float* tokTf          = (float*)(ws + 4784640);          // 131,072
    unsigned short* wdd   = (unsigned short*)(ws + 4915712); // 32,768
    float* p3             = (float*)(ws + 4948480);          // 4,096
    float* m4             = (float*)(ws + 4952576);          // 147,456
    float* st2            = (float*)(ws + 5100032);          // 4,096

    hipFuncSetAttribute((const void*)k1_fused, hipFuncAttributeMaxDynamicSharedMemorySize, K1_LDS);
    hipFuncSetAttribute((const void*)k5_final, hipFuncAttributeMaxDynamicSharedMemorySize, K5_LDS);

    k0_prepack<<<160, 512, 0, stream>>>(tok, wd, tokbf, tokTf, wdd);
    k1_fused<<<B_, 1024, K1_LDS, stream>>>(x, y, tokbf, tokTf, gav, wdd, lnbg, lnbb, z_pre);
    k3a_bn1part<<<512, 256, 0, stream>>>(z_pre, p3);
    k3b_bn1stats<<<1, 64, 0, stream>>>(p3, st1);
    k4m_moments<<<128, 256, 0, stream>>>(z_pre, st1, bn1g, bn1b, m4);
    k4s_bn2stats<<<1, 512, 0, stream>>>(m4, wu, st2);
    k5_final<<<B_, 512, K5_LDS, stream>>>(z_pre, st1, bn1g, bn1b, wu, st2, bn2g, bn2b,
                                          lnpg, lnpb, gate, out);
}